// Round 22
// baseline (132.191 us; speedup 1.0000x reference)
//
#include <hip/hip_runtime.h>
#include <hip/hip_bf16.h>

#define BATCH 8
#define NANCH 261888
#define KPRE 6000
#define PROP 2000
#define CAP 8192
#define NBUCKET 32768
#define MW 94       // u64 words per row actually used (94*64 = 6016 >= 6000)
#define MSTRIDE 96  // padded stride in u64 words; rows are 768B, 64B-aligned
#define WB 8        // mask col-chunk = 8 words = one 64B line per row per block
#define NTILE 156   // full grid per batch (256-row tiles): sum_{ch=0..11} min(24, 2ch+2)
#define R1 2560     // speculative NMS truncation bound (40 words)
#define MW1 40
#define NTILE1 60   // phase-1 (128-row tiles): sum_{ch=0..4} min(20, 4ch+4) = 4+8+12+16+20
#define HB 32       // histogram blocks per batch (fill all 256 CUs)
#define EMAX 1024   // phase-1 edge-list capacity per batch (expected ~100)

typedef unsigned int u32;
typedef unsigned long long u64;
typedef unsigned short u16;

// ---- workspace layout (bytes) ----
#define OFF_COARSE 0ull         // u32[8][HB][256] = 256 KB, fully overwritten by k_hist
#define OFF_META (1ull << 20)   // +0: T[8]; +4096: cnt[b*32]; +16384: done[8];
                                // +16512: ecnt[b*32]; +20480: elist u32[8][EMAX]
#define OFF_CAND (OFF_META + 65536ull)                      // B*CAP*8 = 512 KiB
#define OFF_BOXES (OFF_CAND + (unsigned long long)BATCH * CAP * 8ull)
#define OFF_M ((OFF_BOXES + (unsigned long long)BATCH * KPRE * 16ull + 255ull) & ~255ull)
// hist u16 rows (16 MB, HB=32) live in the M region (36.9 MB, dead until k_mask).

// broadcast lane srclane's 64-bit value to all lanes; srclane must be wave-uniform
// (v_readlane: ignores EXEC, safe under divergence)
__device__ inline u64 bcast64(u64 v, int srclane) {
  int lo = __builtin_amdgcn_readlane((int)(u32)v, srclane);
  int hi = __builtin_amdgcn_readlane((int)(v >> 32), srclane);
  return ((u64)(u32)hi << 32) | (u32)lo;
}

// ---- 1: per-block private LDS histogram; flush u16 row + per-block coarse row (no atomics) ----
__global__ __launch_bounds__(1024) void k_hist(const float* __restrict__ probs, u16* __restrict__ histr,
                                               u32* __restrict__ coarse) {
  __shared__ u32 sh[NBUCKET];  // 128 KiB
  int b = blockIdx.y, blk = blockIdx.x;
  for (int t = threadIdx.x; t < NBUCKET; t += 1024) sh[t] = 0;
  __syncthreads();
  const float4* p4 = (const float4*)(probs + (size_t)b * NANCH * 2);
  const int n4 = NANCH / 2;  // 2 scores per float4
  for (int i = blk * 1024 + threadIdx.x; i < n4; i += HB * 1024) {
    float4 v = p4[i];
    atomicAdd(&sh[__float_as_uint(v.y) >> 15], 1u);
    atomicAdd(&sh[__float_as_uint(v.w) >> 15], 1u);
  }
  __syncthreads();
  u32* dst = (u32*)(histr + ((size_t)b * HB + blk) * NBUCKET);
  for (int t = threadIdx.x; t < NBUCKET / 2; t += 1024)
    dst[t] = (sh[2 * t] & 0xFFFFu) | (sh[2 * t + 1] << 16);
  // per-block coarse 256-bin row: full overwrite (no zero-init, no atomics)
  if (threadIdx.x < 256) {
    int t = threadIdx.x;
    u32 s = 0;
    #pragma unroll 8
    for (int i = 0; i < 128; ++i) s += sh[128 * t + ((i + t) & 127)];
    coarse[((size_t)b * HB + blk) * 256 + t] = s;
  }
}

// ---- 2: find threshold bucket T (sum per-block coarse rows) + zero cnt/ecnt/done ----
__global__ __launch_bounds__(256) void k_thresh(const u16* __restrict__ histr, const u32* __restrict__ coarse,
                                                int* __restrict__ meta, int* __restrict__ cnt,
                                                int* __restrict__ ecnt, int* __restrict__ done) {
  __shared__ u32 cg[256];
  __shared__ int bt[128];
  __shared__ int s_c, s_sfx;
  int b = blockIdx.x;
  int t = threadIdx.x;
  {
    u32 s = 0;
    for (int r = 0; r < HB; ++r) s += coarse[((size_t)b * HB + r) * 256 + t];
    cg[t] = s;
  }
  if (t == 1) { cnt[b * 32] = 0; ecnt[b * 32] = 0; done[b] = 0; }  // pre-k_compact zeroing
  __syncthreads();
  if (t == 0) {
    int suffix = 0, c = 0;
    for (int cc = 255; cc >= 0; --cc) {
      int ns = suffix + (int)cg[cc];
      if (ns >= KPRE) { c = cc; break; }
      suffix = ns;
    }
    s_c = c; s_sfx = suffix;
  }
  __syncthreads();
  int cstar = s_c;
  if (t < 128) {
    const u16* hb = histr + (size_t)b * HB * NBUCKET;
    int bsum = 0;
    for (int r = 0; r < HB; ++r) bsum += hb[(size_t)r * NBUCKET + cstar * 128 + t];
    bt[t] = bsum;
  }
  __syncthreads();
  if (t == 0) {
    int run = s_sfx, T = 0;
    for (int k = 127; k >= 0; --k) {
      run += bt[k];
      if (run >= KPRE) { T = cstar * 128 + k; break; }
    }
    meta[b] = T;
  }
}

// ---- 3: compact candidates (bucket >= T); ballot -> LDS -> 1 global atomic/block ----
__global__ __launch_bounds__(256) void k_compact(const float* __restrict__ probs, const int* __restrict__ meta,
                                                 int* __restrict__ cnt, u64* __restrict__ cand) {
  __shared__ int wbase[4];
  __shared__ int btot, bbase;
  int b = blockIdx.y;
  int T = meta[b];
  const int n4 = NANCH / 2;
  int i = blockIdx.x * 256 + threadIdx.x;
  int lane = threadIdx.x & 63, wv = threadIdx.x >> 6;
  if (threadIdx.x == 0) btot = 0;
  __syncthreads();
  u32 bits0 = 0, bits1 = 0;
  bool p0 = false, p1 = false;
  if (i < n4) {
    float4 v = ((const float4*)(probs + (size_t)b * NANCH * 2))[i];
    bits0 = __float_as_uint(v.y); bits1 = __float_as_uint(v.w);
    p0 = (int)(bits0 >> 15) >= T; p1 = (int)(bits1 >> 15) >= T;
  }
  u64 m0 = __ballot(p0);
  u64 m1 = __ballot(p1);
  int c0 = (int)__popcll(m0), c1 = (int)__popcll(m1);
  if (lane == 0) wbase[wv] = (c0 + c1) ? atomicAdd(&btot, c0 + c1) : 0;
  __syncthreads();
  if (threadIdx.x == 0 && btot) bbase = atomicAdd(&cnt[b * 32], btot);
  __syncthreads();
  if (p0 | p1) {
    int base = bbase + wbase[wv];
    if (p0) {
      int pos = base + (int)__popcll(m0 & ((1ull << lane) - 1ull));
      if (pos < CAP) cand[(size_t)b * CAP + pos] = ((u64)bits0 << 32) | (u32)(~(u32)(2 * i));
    }
    if (p1) {
      int pos = base + c0 + (int)__popcll(m1 & ((1ull << lane) - 1ull));
      if (pos < CAP) cand[(size_t)b * CAP + pos] = ((u64)bits1 << 32) | (u32)(~(u32)(2 * i + 1));
    }
  }
}

// ---- 4a: local bitonic sort of 1024-element runs (desc), 8 runs per batch ----
__global__ __launch_bounds__(1024) void k_lsort(u64* __restrict__ cand, const int* __restrict__ cnt) {
  __shared__ u64 sk[1024];  // 8 KiB
  int b = blockIdx.y, run = blockIdx.x;
  int C = cnt[b * 32];
  int g = run * 1024 + threadIdx.x;
  sk[threadIdx.x] = (g < C) ? cand[(size_t)b * CAP + g] : 0ull;
  __syncthreads();
  for (int ksz = 2; ksz <= 1024; ksz <<= 1) {
    for (int j = ksz >> 1; j > 0; j >>= 1) {
      int i = threadIdx.x;
      int ixj = i ^ j;
      if (ixj > i) {
        u64 a = sk[i], c2 = sk[ixj];
        bool up = (i & ksz) == 0;
        if ((a < c2) == up) { sk[i] = c2; sk[ixj] = a; }  // descending
      }
      __syncthreads();
    }
  }
  cand[(size_t)b * CAP + g] = sk[threadIdx.x];
}

// merge-path partition for DESCENDING keys, stable toward X (uses >=)
__device__ inline int mp_search(const u64* X, int n1, const u64* Y, int n2, int d) {
  int lo = d - n2; if (lo < 0) lo = 0;
  int hi = d < n1 ? d : n1;
  while (lo < hi) {
    int m = (lo + hi) >> 1;
    if (X[m] >= Y[d - 1 - m]) lo = m + 1; else hi = m;
  }
  return lo;
}

// ---- 4b: merge 8 sorted 1024-runs -> top-6000, fused gather + box decode ----
__global__ __launch_bounds__(1024) void k_merge(const u64* __restrict__ cand,
                                                const float* __restrict__ anchors, const float* __restrict__ bbox,
                                                float4* __restrict__ boxes) {
  __shared__ u64 A[CAP];   // 64 KiB
  __shared__ u64 Bf[CAP];  // 64 KiB
  int b = blockIdx.y;
  int mhalf = blockIdx.x;
  int t = threadIdx.x;
  for (int r = t; r < CAP; r += 1024) A[r] = cand[(size_t)b * CAP + r];
  __syncthreads();
  {
    int m = t >> 8, tt = t & 255;
    const u64* X = A + m * 2048; const u64* Y = X + 1024;
    u64* O = Bf + m * 2048;
    int d = tt * 8;
    int i = mp_search(X, 1024, Y, 1024, d), j = d - i;
    #pragma unroll
    for (int k = 0; k < 8; ++k) {
      bool tx = (i < 1024) && (j >= 1024 || X[i] >= Y[j]);
      O[d + k] = tx ? X[i++] : Y[j++];
    }
  }
  __syncthreads();
  {
    int m = t >> 9, tt = t & 511;
    const u64* X = Bf + m * 4096; const u64* Y = X + 2048;
    u64* O = A + m * 4096;
    int d = tt * 8;
    int i = mp_search(X, 2048, Y, 2048, d), j = d - i;
    #pragma unroll
    for (int k = 0; k < 8; ++k) {
      bool tx = (i < 2048) && (j >= 2048 || X[i] >= Y[j]);
      O[d + k] = tx ? X[i++] : Y[j++];
    }
  }
  __syncthreads();
  {
    const u64* X = A; const u64* Y = A + 4096;
    int d = mhalf * 3000 + t * 3;
    if (t < 1000) {
      int i = mp_search(X, 4096, Y, 4096, d), j = d - i;
      #pragma unroll
      for (int k = 0; k < 3; ++k) {
        bool tx = (i < 4096) && (j >= 4096 || X[i] >= Y[j]);
        u64 key = tx ? X[i++] : Y[j++];
        u32 idx = ~(u32)key;
        const float4 a  = ((const float4*)anchors)[(size_t)b * NANCH + idx];
        const float4 dr = ((const float4*)bbox)[(size_t)b * NANCH + idx];
        float d0 = __fmul_rn(dr.x, 0.1f), d1 = __fmul_rn(dr.y, 0.1f);
        float d2 = __fmul_rn(dr.z, 0.2f), d3 = __fmul_rn(dr.w, 0.2f);
        float h = __fsub_rn(a.z, a.x);
        float w = __fsub_rn(a.w, a.y);
        float cy = __fadd_rn(a.x, __fmul_rn(0.5f, h));
        float cx = __fadd_rn(a.y, __fmul_rn(0.5f, w));
        cy = __fadd_rn(cy, __fmul_rn(d0, h));
        cx = __fadd_rn(cx, __fmul_rn(d1, w));
        h = __fmul_rn(h, (float)exp((double)d2));
        w = __fmul_rn(w, (float)exp((double)d3));
        float y1 = __fsub_rn(cy, __fmul_rn(0.5f, h));
        float x1 = __fsub_rn(cx, __fmul_rn(0.5f, w));
        float4 o; o.x = y1; o.y = x1; o.z = __fadd_rn(y1, h); o.w = __fadd_rn(x1, w);
        boxes[(size_t)b * KPRE + d + k] = o;
      }
    }
  }
}

// ---- 5: suppression bitmask (R8 structure), TRBS rows per tile, blockDim = TRBS.
// EDGES=true (phase 1): emit sparse edge list, no M writes. EDGES=false (phase 2): dense M. ----
template<int TRBS, int TNRB, int TNCH, int TNTILE, bool EDGES>
__global__ __launch_bounds__(256) void k_mask_t(const float4* __restrict__ boxes, u64* __restrict__ M,
                                                u32* __restrict__ elist, int* __restrict__ ecnt,
                                                const int* __restrict__ done) {
  if (!EDGES && done[blockIdx.y]) return;
  const double MD = (double)0.7f + 0x1.0p-25;
  const float CHI = 0.700001f, CLO = 0.699999f;
  const int RPC = 512 / TRBS;  // rowblocks unlocked per chunk step
  __shared__ float4 sb[WB * 64];
  __shared__ float  sa[WB * 64];
  int b = blockIdx.y;
  int tile = TNTILE - 1 - blockIdx.x;  // heavy tiles dispatched first
  int ch = 0, base = 0;
  #pragma unroll
  for (int j = 0; j < TNCH; ++j) {
    int n = RPC * (j + 1); if (n > TNRB) n = TNRB;
    if (tile >= base + n) { base += n; ch = j + 1; }
  }
  int rb = tile - base;

  int w0 = ch * WB;
  int c0 = w0 << 6;
  const float4* bb = boxes + (size_t)b * KPRE;

  for (int t = threadIdx.x; t < WB * 64; t += TRBS) {
    int c = c0 + t;
    float4 v; v.x = 0.f; v.y = 0.f; v.z = 0.f; v.w = 0.f;
    if (c < KPRE) v = bb[c];
    sb[t] = v;
    sa[t] = __fmul_rn(__fsub_rn(v.z, v.x), __fsub_rn(v.w, v.y));
  }
  __syncthreads();

  int half = threadIdx.x & 1;
  int r0 = rb * TRBS + (threadIdx.x >> 1);
  int r1 = r0 + TRBS / 2;
  bool v0 = r0 < KPRE, v1 = r1 < KPRE;
  float4 z4; z4.x = 0.f; z4.y = 0.f; z4.z = 0.f; z4.w = 0.f;
  float4 br0 = v0 ? bb[r0] : z4;
  float4 br1 = v1 ? bb[r1] : z4;
  float ar0 = __fmul_rn(__fsub_rn(br0.z, br0.x), __fsub_rn(br0.w, br0.y));
  float ar1 = __fmul_rn(__fsub_rn(br1.z, br1.x), __fsub_rn(br1.w, br1.y));
  int wbase = w0 + 4 * half;

  u64 buf0[4], buf1[4];
  #pragma unroll
  for (int k = 0; k < 4; ++k) {
    int w = wbase + k;
    int cbase = w << 6;
    int tb = (w - w0) << 6;
    bool n0 = v0 && (w < MW) && (cbase + 63 > r0);
    bool n1 = v1 && (w < MW) && (cbase + 63 > r1);
    u64 bits0 = 0ull, bits1 = 0ull;
    if (n0 | n1) {
      u64 amb0 = 0ull, amb1 = 0ull;
      #pragma unroll 16
      for (int k2 = 0; k2 < 64; ++k2) {
        float4 bc = sb[tb + k2];
        float ac = sa[tb + k2];
        {
          float iy1 = fmaxf(br0.x, bc.x), ix1 = fmaxf(br0.y, bc.y);
          float iy2 = fminf(br0.z, bc.z), ix2 = fminf(br0.w, bc.w);
          float ih = fmaxf(__fsub_rn(iy2, iy1), 0.f), iw = fmaxf(__fsub_rn(ix2, ix1), 0.f);
          float inter = __fmul_rn(ih, iw);
          float uni = __fsub_rn(__fadd_rn(ar0, ac), inter);
          bool hi = inter >= __fmul_rn(uni, CHI);
          bool lo = inter >= __fmul_rn(uni, CLO);
          if (hi) bits0 |= (1ull << k2);
          if (lo != hi) amb0 |= (1ull << k2);
        }
        {
          float iy1 = fmaxf(br1.x, bc.x), ix1 = fmaxf(br1.y, bc.y);
          float iy2 = fminf(br1.z, bc.z), ix2 = fminf(br1.w, bc.w);
          float ih = fmaxf(__fsub_rn(iy2, iy1), 0.f), iw = fmaxf(__fsub_rn(ix2, ix1), 0.f);
          float inter = __fmul_rn(ih, iw);
          float uni = __fsub_rn(__fadd_rn(ar1, ac), inter);
          bool hi = inter >= __fmul_rn(uni, CHI);
          bool lo = inter >= __fmul_rn(uni, CLO);
          if (hi) bits1 |= (1ull << k2);
          if (lo != hi) amb1 |= (1ull << k2);
        }
      }
      while (amb0) {  // exact f64 fallback for ambiguous-band columns (rare)
        int k2 = (int)__builtin_ctzll(amb0); amb0 &= amb0 - 1;
        float4 bc = sb[tb + k2]; float ac = sa[tb + k2];
        float iy1 = fmaxf(br0.x, bc.x), ix1 = fmaxf(br0.y, bc.y);
        float iy2 = fminf(br0.z, bc.z), ix2 = fminf(br0.w, bc.w);
        float ih = fmaxf(__fsub_rn(iy2, iy1), 0.f), iw = fmaxf(__fsub_rn(ix2, ix1), 0.f);
        float inter = __fmul_rn(ih, iw);
        float uni = __fsub_rn(__fadd_rn(ar0, ac), inter);
        if ((double)inter >= MD * (double)uni) bits0 |= (1ull << k2);
      }
      while (amb1) {
        int k2 = (int)__builtin_ctzll(amb1); amb1 &= amb1 - 1;
        float4 bc = sb[tb + k2]; float ac = sa[tb + k2];
        float iy1 = fmaxf(br1.x, bc.x), ix1 = fmaxf(br1.y, bc.y);
        float iy2 = fminf(br1.z, bc.z), ix2 = fminf(br1.w, bc.w);
        float ih = fmaxf(__fsub_rn(iy2, iy1), 0.f), iw = fmaxf(__fsub_rn(ix2, ix1), 0.f);
        float inter = __fmul_rn(ih, iw);
        float uni = __fsub_rn(__fadd_rn(ar1, ac), inter);
        if ((double)inter >= MD * (double)uni) bits1 |= (1ull << k2);
      }
      if (n0 && cbase <= r0) bits0 &= ~((r0 - cbase >= 63) ? ~0ull : ((1ull << (r0 - cbase + 1)) - 1ull));
      if (n1 && cbase <= r1) bits1 &= ~((r1 - cbase >= 63) ? ~0ull : ((1ull << (r1 - cbase + 1)) - 1ull));
    }
    if (EDGES) {
      // guard with n0/n1: sub-diagonal (c <= r) garbage bits must NOT become edges
      u64 e0 = n0 ? bits0 : 0ull;
      while (e0) {
        int k2 = (int)__builtin_ctzll(e0); e0 &= e0 - 1;
        int pos = atomicAdd(&ecnt[b * 32], 1);
        if (pos < EMAX) elist[(size_t)b * EMAX + pos] = ((u32)r0 << 13) | (u32)(cbase + k2);
      }
      u64 e1 = n1 ? bits1 : 0ull;
      while (e1) {
        int k2 = (int)__builtin_ctzll(e1); e1 &= e1 - 1;
        int pos = atomicAdd(&ecnt[b * 32], 1);
        if (pos < EMAX) elist[(size_t)b * EMAX + pos] = ((u32)r1 << 13) | (u32)(cbase + k2);
      }
    } else {
      buf0[k] = n0 ? bits0 : 0ull;
      buf1[k] = n1 ? bits1 : 0ull;
    }
  }
  if (!EDGES) {
    if (v0) {
      ulonglong2* dst = (ulonglong2*)(M + ((size_t)b * KPRE + r0) * MSTRIDE + wbase);
      ulonglong2 p; p.x = buf0[0]; p.y = buf0[1]; dst[0] = p;
      p.x = buf0[2]; p.y = buf0[3]; dst[1] = p;
    }
    if (v1) {
      ulonglong2* dst = (ulonglong2*)(M + ((size_t)b * KPRE + r1) * MSTRIDE + wbase);
      ulonglong2 p; p.x = buf1[0]; p.y = buf1[1]; dst[0] = p;
      p.x = buf1[2]; p.y = buf1[3]; dst[1] = p;
    }
  }
}

// ---- 6a: PHASE-1 scan via Jacobi fixpoint on the sparse suppression DAG ----
template<int TMW>  // TMW <= 64, R1 = TMW*64
__global__ __launch_bounds__(64) void k_scan1(const u32* __restrict__ elist, const int* __restrict__ ecnt,
                                              const float4* __restrict__ boxes, float4* __restrict__ out,
                                              int* __restrict__ done) {
  __shared__ u32 se[EMAX];       // 4 KiB
  __shared__ u64 skw[TMW];       // keep words (LDS: exec-safe reads)
  __shared__ u32 su32[TMW * 2];  // suppression accumulator (u32 halves for LDS atomicOr)
  __shared__ int pfx[TMW];
  __shared__ int s_tot;
  int b = blockIdx.x;
  int lane = threadIdx.x;  // 0..63
  int E = ecnt[b * 32];
  if (E > EMAX) return;  // overflow -> fallback

  for (int i = lane; i < E; i += 64) se[i] = elist[(size_t)b * EMAX + i];
  u64 kw = (lane < TMW) ? ~0ull : 0ull;
  if (lane < TMW) skw[lane] = kw;
  bool conv = false;
  __syncthreads();

  for (int iter = 0; iter < 64 && !conv; ++iter) {
    for (int i = lane; i < TMW * 2; i += 64) su32[i] = 0u;
    __syncthreads();
    for (int i = lane; i < E; i += 64) {
      u32 v = se[i];
      int r = (int)(v >> 13), c = (int)(v & 8191u);
      if ((skw[r >> 6] >> (r & 63)) & 1ull)
        atomicOr(&su32[c >> 5], 1u << (c & 31));
    }
    __syncthreads();
    u64 nkw = kw;
    if (lane < TMW)
      nkw = ~((u64)su32[2 * lane] | ((u64)su32[2 * lane + 1] << 32));
    u64 chg = __ballot(nkw != kw);
    kw = nkw;
    if (lane < TMW) skw[lane] = kw;  // no cross-lane skw reads until after next barrier
    if (chg == 0ull) conv = true;
    __syncthreads();
  }
  if (!conv) return;  // no certified fixpoint -> fallback (done stays 0)

  if (lane == 0) {
    int s = 0;
    for (int t = 0; t < TMW; ++t) { pfx[t] = s; s += (int)__popcll(skw[t]); }
    s_tot = s;
  }
  __syncthreads();

  if (s_tot < PROP) return;  // not enough keeps within R1 -> fallback (done stays 0)
  if (lane == 0) done[b] = 1;

  const float4* bb = boxes + (size_t)b * KPRE;
  float4* ob = out + (size_t)b * PROP;
  if (lane < TMW) {
    u64 bits = kw;
    int slot = pfx[lane];
    while (bits && slot < PROP) {
      int k = (int)__builtin_ctzll(bits);
      ob[slot] = bb[(lane << 6) + k];
      ++slot;
      bits &= bits - 1;
    }
  }
}

// ---- 6b: PHASE-2 fallback scan (proven R12 4-wave depth-1 pipeline), early-exits on done ----
template<int TMW>
__global__ __launch_bounds__(256) void k_scan_t(const u64* __restrict__ M, const float4* __restrict__ boxes,
                                                float4* __restrict__ out, int* __restrict__ done) {
  if (done[blockIdx.x]) return;
  __shared__ u64 xch[2][4];
  __shared__ u64 fin[TMW];
  __shared__ int pfx[TMW];
  __shared__ int s_tot;
  const int NL = (TMW + 1) / 2;  // lanes holding keep-words (2 per lane)
  int b = blockIdx.x;
  int tid = threadIdx.x;
  int lane = tid & 63;
  int wv = tid >> 6;
  const u64* Mb = M + (size_t)b * KPRE * MSTRIDE;

  if (tid < TMW) fin[tid] = 0ull;

  u64 kw0 = ~0ull, kw1 = ~0ull;
  u64 cur = ~0ull;
  u64 dw = Mb[(size_t)lane * MSTRIDE + 0];
  int count = 0;
  ulonglong2 mmA[16], mmB[16];

  {
    bool la = (lane < NL);
    #pragma unroll
    for (int kk = 0; kk < 16; ++kk) {
      int r = wv + (kk << 2);
      ulonglong2 t2; t2.x = 0ull; t2.y = 0ull;
      if (la && r < KPRE) t2 = ((const ulonglong2*)(Mb + (size_t)r * MSTRIDE))[lane];
      mmA[kk] = t2;
    }
  }

#define SCAN_BODY(MMCUR, MMNXT)                                                         \
  {                                                                                     \
    int rem = KPRE - (w << 6);                                                          \
    u64 valid = (rem >= 64) ? ~0ull : ((1ull << rem) - 1ull);                           \
    cur &= valid;                                                                       \
    u64 nz = __ballot(dw != 0ull);                                                      \
    u64 pend = cur & nz;                                                                \
    while (pend) {                                                                      \
      int k = (int)__builtin_ctzll(pend);                                               \
      u64 d = bcast64(dw, k);                                                           \
      cur &= ~d;                                                                        \
      pend &= (pend - 1);                                                               \
      pend &= cur;                                                                      \
    }                                                                                   \
    if (tid == 0) fin[w] = cur;                                                         \
    count += (int)__popcll(cur);                                                        \
    if (count >= PROP || w == TMW - 1) break;                                           \
    {                                                                                   \
      int rn = ((w + 1) << 6) + lane;                                                   \
      dw = (rn < KPRE) ? Mb[(size_t)rn * MSTRIDE + (w + 1)] : 0ull;                     \
    }                                                                                   \
    {                                                                                   \
      bool la = (lane < NL) && (2 * lane + 1 >= w + 2);                                 \
      _Pragma("unroll")                                                                 \
      for (int kk = 0; kk < 16; ++kk) {                                                 \
        int r = ((w + 1) << 6) + wv + (kk << 2);                                        \
        ulonglong2 t2; t2.x = 0ull; t2.y = 0ull;                                        \
        if (la && r < KPRE) t2 = ((const ulonglong2*)(Mb + (size_t)r * MSTRIDE))[lane]; \
        MMNXT[kk] = t2;                                                                 \
      }                                                                                 \
    }                                                                                   \
    _Pragma("unroll")                                                                   \
    for (int kk = 0; kk < 16; ++kk) {                                                   \
      int k = wv + (kk << 2);                                                           \
      u64 sel = 0ull - ((cur >> k) & 1ull);                                             \
      kw0 &= ~(MMCUR[kk].x & sel);                                                      \
      kw1 &= ~(MMCUR[kk].y & sel);                                                      \
    }                                                                                   \
    int nw = w + 1;                                                                     \
    if (lane == (nw >> 1)) xch[nw & 1][wv] = (nw & 1) ? kw1 : kw0;                      \
    asm volatile("s_waitcnt lgkmcnt(0)" ::: "memory");                                  \
    __builtin_amdgcn_sched_barrier(0);                                                  \
    __builtin_amdgcn_s_barrier();                                                       \
    __builtin_amdgcn_sched_barrier(0);                                                  \
    cur = xch[nw & 1][0] & xch[nw & 1][1] & xch[nw & 1][2] & xch[nw & 1][3];            \
  }

  for (int w = 0; w < TMW; ++w) {
    if ((w & 1) == 0) SCAN_BODY(mmA, mmB)
    else              SCAN_BODY(mmB, mmA)
  }
#undef SCAN_BODY
  __syncthreads();

  if (tid == 0) {
    int s = 0;
    for (int t = 0; t < TMW; ++t) { pfx[t] = s; s += (int)__popcll(fin[t]); }
    s_tot = (s < PROP) ? s : PROP;
  }
  __syncthreads();

  const float4* bb = boxes + (size_t)b * KPRE;
  float4* ob = out + (size_t)b * PROP;
  if (tid < TMW) {
    u64 bits = fin[tid];
    int slot = pfx[tid];
    while (bits && slot < PROP) {
      int k = (int)__builtin_ctzll(bits);
      ob[slot] = bb[(tid << 6) + k];
      ++slot;
      bits &= bits - 1;
    }
  }
  {
    float4 z; z.x = 0.f; z.y = 0.f; z.z = 0.f; z.w = 0.f;
    for (int i = s_tot + tid; i < PROP; i += 256) ob[i] = z;
  }
}

extern "C" void kernel_launch(void* const* d_in, const int* in_sizes, int n_in,
                              void* d_out, int out_size, void* d_ws, size_t ws_size,
                              hipStream_t stream) {
  const float* probs   = (const float*)d_in[0];
  const float* bbox    = (const float*)d_in[1];
  const float* anchors = (const float*)d_in[2];
  char* ws = (char*)d_ws;
  u32* coarse  = (u32*)(ws + OFF_COARSE);        // u32[8][HB][256], fully overwritten
  int* meta    = (int*)(ws + OFF_META);          // T[8]
  int* cnt     = (int*)(ws + OFF_META + 4096);   // cnt[b*32], 128B-padded
  int* done    = (int*)(ws + OFF_META + 16384);  // done[8]
  int* ecnt    = (int*)(ws + OFF_META + 16512);  // ecnt[b*32], 128B-padded
  u32* elist   = (u32*)(ws + OFF_META + 20480);  // u32[8][EMAX] = 32 KB
  u64* cand    = (u64*)(ws + OFF_CAND);
  float4* boxes = (float4*)(ws + OFF_BOXES);
  u64* M       = (u64*)(ws + OFF_M);
  u16* histr   = (u16*)(ws + OFF_M);             // reuse M region (dead until k_mask)
  float4* out  = (float4*)d_out;

  // no hipMemsetAsync: coarse is fully overwritten by k_hist; cnt/ecnt/done zeroed by k_thresh.

  dim3 gh(HB, BATCH);
  k_hist<<<gh, 1024, 0, stream>>>(probs, histr, coarse);
  k_thresh<<<BATCH, 256, 0, stream>>>(histr, coarse, meta, cnt, ecnt, done);
  dim3 gc((NANCH / 2 + 255) / 256, BATCH);
  k_compact<<<gc, 256, 0, stream>>>(probs, meta, cnt, cand);
  dim3 gl(8, BATCH);
  k_lsort<<<gl, 1024, 0, stream>>>(cand, cnt);
  dim3 gmr(2, BATCH);
  k_merge<<<gmr, 1024, 0, stream>>>(cand, anchors, bbox, boxes);

  // phase 1: 128-row tiles (60/batch, 480 blocks of 128 thr) -> ~2 blocks/CU, halved tail
  dim3 g1(NTILE1, BATCH);
  k_mask_t<128, R1 / 128, MW1 / 8, NTILE1, true><<<g1, 128, 0, stream>>>(boxes, M, elist, ecnt, done);
  k_scan1<MW1><<<BATCH, 64, 0, stream>>>(elist, ecnt, boxes, out, done);

  // phase 2: exact fallback (256-row tiles; early-exits per batch when done)
  dim3 g2(NTILE, BATCH);
  k_mask_t<256, 24, 12, NTILE, false><<<g2, 256, 0, stream>>>(boxes, M, elist, ecnt, done);
  k_scan_t<MW><<<BATCH, 256, 0, stream>>>(M, boxes, out, done);
}

// Round 23
// 113.214 us; speedup vs baseline: 1.1676x; 1.1676x over previous
//
#include <hip/hip_runtime.h>
#include <hip/hip_bf16.h>

#define BATCH 8
#define NANCH 261888
#define KPRE 6000
#define PROP 2000
#define CAP 8192
#define NBUCKET 32768
#define MW 94       // u64 words per row actually used (94*64 = 6016 >= 6000)
#define MSTRIDE 96  // padded stride in u64 words; rows are 768B, 64B-aligned
#define NTILE 156   // phase-2 grid per batch (8-word tiles): sum_{ch=0..11} min(24, 2ch+2)
#define R1 2560     // speculative NMS truncation bound (40 words)
#define MW1 40
#define NTILE1 55   // phase-1 (4-word tiles, 256 rows): sum_{ch=0..9} min(10, ch+1)
#define HB 32       // histogram blocks per batch (fill all 256 CUs)
#define EMAX 1024   // phase-1 edge-list capacity per batch (expected ~100)

typedef unsigned int u32;
typedef unsigned long long u64;
typedef unsigned short u16;

// ---- workspace layout (bytes) ----
#define OFF_COARSE 0ull         // u32[8][HB][256] = 256 KB, fully overwritten by k_hist
#define OFF_META (1ull << 20)   // +0: T[8]; +4096: cnt[b*32]; +16384: done[8];
                                // +16512: ecnt[b*32]; +20480: elist u32[8][EMAX]
#define OFF_CAND (OFF_META + 65536ull)                      // B*CAP*8 = 512 KiB
#define OFF_BOXES (OFF_CAND + (unsigned long long)BATCH * CAP * 8ull)
#define OFF_M ((OFF_BOXES + (unsigned long long)BATCH * KPRE * 16ull + 255ull) & ~255ull)
// hist u16 rows (16 MB, HB=32) live in the M region (36.9 MB, dead until k_mask).

// broadcast lane srclane's 64-bit value to all lanes; srclane must be wave-uniform
// (v_readlane: ignores EXEC, safe under divergence)
__device__ inline u64 bcast64(u64 v, int srclane) {
  int lo = __builtin_amdgcn_readlane((int)(u32)v, srclane);
  int hi = __builtin_amdgcn_readlane((int)(v >> 32), srclane);
  return ((u64)(u32)hi << 32) | (u32)lo;
}

// ---- 1: per-block private LDS histogram; flush u16 row + per-block coarse row (no atomics) ----
__global__ __launch_bounds__(1024) void k_hist(const float* __restrict__ probs, u16* __restrict__ histr,
                                               u32* __restrict__ coarse) {
  __shared__ u32 sh[NBUCKET];  // 128 KiB
  int b = blockIdx.y, blk = blockIdx.x;
  for (int t = threadIdx.x; t < NBUCKET; t += 1024) sh[t] = 0;
  __syncthreads();
  const float4* p4 = (const float4*)(probs + (size_t)b * NANCH * 2);
  const int n4 = NANCH / 2;  // 2 scores per float4
  for (int i = blk * 1024 + threadIdx.x; i < n4; i += HB * 1024) {
    float4 v = p4[i];
    atomicAdd(&sh[__float_as_uint(v.y) >> 15], 1u);
    atomicAdd(&sh[__float_as_uint(v.w) >> 15], 1u);
  }
  __syncthreads();
  u32* dst = (u32*)(histr + ((size_t)b * HB + blk) * NBUCKET);
  for (int t = threadIdx.x; t < NBUCKET / 2; t += 1024)
    dst[t] = (sh[2 * t] & 0xFFFFu) | (sh[2 * t + 1] << 16);
  // per-block coarse 256-bin row: full overwrite (no zero-init, no atomics)
  if (threadIdx.x < 256) {
    int t = threadIdx.x;
    u32 s = 0;
    #pragma unroll 8
    for (int i = 0; i < 128; ++i) s += sh[128 * t + ((i + t) & 127)];
    coarse[((size_t)b * HB + blk) * 256 + t] = s;
  }
}

// ---- 2: find threshold bucket T (sum per-block coarse rows) + zero cnt/ecnt/done ----
__global__ __launch_bounds__(256) void k_thresh(const u16* __restrict__ histr, const u32* __restrict__ coarse,
                                                int* __restrict__ meta, int* __restrict__ cnt,
                                                int* __restrict__ ecnt, int* __restrict__ done) {
  __shared__ u32 cg[256];
  __shared__ int bt[128];
  __shared__ int s_c, s_sfx;
  int b = blockIdx.x;
  int t = threadIdx.x;
  {
    u32 s = 0;
    for (int r = 0; r < HB; ++r) s += coarse[((size_t)b * HB + r) * 256 + t];
    cg[t] = s;
  }
  if (t == 1) { cnt[b * 32] = 0; ecnt[b * 32] = 0; done[b] = 0; }  // pre-k_compact zeroing
  __syncthreads();
  if (t == 0) {
    int suffix = 0, c = 0;
    for (int cc = 255; cc >= 0; --cc) {
      int ns = suffix + (int)cg[cc];
      if (ns >= KPRE) { c = cc; break; }
      suffix = ns;
    }
    s_c = c; s_sfx = suffix;
  }
  __syncthreads();
  int cstar = s_c;
  if (t < 128) {
    const u16* hb = histr + (size_t)b * HB * NBUCKET;
    int bsum = 0;
    for (int r = 0; r < HB; ++r) bsum += hb[(size_t)r * NBUCKET + cstar * 128 + t];
    bt[t] = bsum;
  }
  __syncthreads();
  if (t == 0) {
    int run = s_sfx, T = 0;
    for (int k = 127; k >= 0; --k) {
      run += bt[k];
      if (run >= KPRE) { T = cstar * 128 + k; break; }
    }
    meta[b] = T;
  }
}

// ---- 3: compact candidates (bucket >= T); ballot -> LDS -> 1 global atomic/block ----
__global__ __launch_bounds__(256) void k_compact(const float* __restrict__ probs, const int* __restrict__ meta,
                                                 int* __restrict__ cnt, u64* __restrict__ cand) {
  __shared__ int wbase[4];
  __shared__ int btot, bbase;
  int b = blockIdx.y;
  int T = meta[b];
  const int n4 = NANCH / 2;
  int i = blockIdx.x * 256 + threadIdx.x;
  int lane = threadIdx.x & 63, wv = threadIdx.x >> 6;
  if (threadIdx.x == 0) btot = 0;
  __syncthreads();
  u32 bits0 = 0, bits1 = 0;
  bool p0 = false, p1 = false;
  if (i < n4) {
    float4 v = ((const float4*)(probs + (size_t)b * NANCH * 2))[i];
    bits0 = __float_as_uint(v.y); bits1 = __float_as_uint(v.w);
    p0 = (int)(bits0 >> 15) >= T; p1 = (int)(bits1 >> 15) >= T;
  }
  u64 m0 = __ballot(p0);
  u64 m1 = __ballot(p1);
  int c0 = (int)__popcll(m0), c1 = (int)__popcll(m1);
  if (lane == 0) wbase[wv] = (c0 + c1) ? atomicAdd(&btot, c0 + c1) : 0;
  __syncthreads();
  if (threadIdx.x == 0 && btot) bbase = atomicAdd(&cnt[b * 32], btot);
  __syncthreads();
  if (p0 | p1) {
    int base = bbase + wbase[wv];
    if (p0) {
      int pos = base + (int)__popcll(m0 & ((1ull << lane) - 1ull));
      if (pos < CAP) cand[(size_t)b * CAP + pos] = ((u64)bits0 << 32) | (u32)(~(u32)(2 * i));
    }
    if (p1) {
      int pos = base + c0 + (int)__popcll(m1 & ((1ull << lane) - 1ull));
      if (pos < CAP) cand[(size_t)b * CAP + pos] = ((u64)bits1 << 32) | (u32)(~(u32)(2 * i + 1));
    }
  }
}

// ---- 4a: local bitonic sort of 1024-element runs (desc), 8 runs per batch ----
__global__ __launch_bounds__(1024) void k_lsort(u64* __restrict__ cand, const int* __restrict__ cnt) {
  __shared__ u64 sk[1024];  // 8 KiB
  int b = blockIdx.y, run = blockIdx.x;
  int C = cnt[b * 32];
  int g = run * 1024 + threadIdx.x;
  sk[threadIdx.x] = (g < C) ? cand[(size_t)b * CAP + g] : 0ull;
  __syncthreads();
  for (int ksz = 2; ksz <= 1024; ksz <<= 1) {
    for (int j = ksz >> 1; j > 0; j >>= 1) {
      int i = threadIdx.x;
      int ixj = i ^ j;
      if (ixj > i) {
        u64 a = sk[i], c2 = sk[ixj];
        bool up = (i & ksz) == 0;
        if ((a < c2) == up) { sk[i] = c2; sk[ixj] = a; }  // descending
      }
      __syncthreads();
    }
  }
  cand[(size_t)b * CAP + g] = sk[threadIdx.x];
}

// merge-path partition for DESCENDING keys, stable toward X (uses >=)
__device__ inline int mp_search(const u64* X, int n1, const u64* Y, int n2, int d) {
  int lo = d - n2; if (lo < 0) lo = 0;
  int hi = d < n1 ? d : n1;
  while (lo < hi) {
    int m = (lo + hi) >> 1;
    if (X[m] >= Y[d - 1 - m]) lo = m + 1; else hi = m;
  }
  return lo;
}

// ---- 4b: merge 8 sorted 1024-runs -> top-6000, fused gather + box decode ----
__global__ __launch_bounds__(1024) void k_merge(const u64* __restrict__ cand,
                                                const float* __restrict__ anchors, const float* __restrict__ bbox,
                                                float4* __restrict__ boxes) {
  __shared__ u64 A[CAP];   // 64 KiB
  __shared__ u64 Bf[CAP];  // 64 KiB
  int b = blockIdx.y;
  int mhalf = blockIdx.x;
  int t = threadIdx.x;
  for (int r = t; r < CAP; r += 1024) A[r] = cand[(size_t)b * CAP + r];
  __syncthreads();
  {
    int m = t >> 8, tt = t & 255;
    const u64* X = A + m * 2048; const u64* Y = X + 1024;
    u64* O = Bf + m * 2048;
    int d = tt * 8;
    int i = mp_search(X, 1024, Y, 1024, d), j = d - i;
    #pragma unroll
    for (int k = 0; k < 8; ++k) {
      bool tx = (i < 1024) && (j >= 1024 || X[i] >= Y[j]);
      O[d + k] = tx ? X[i++] : Y[j++];
    }
  }
  __syncthreads();
  {
    int m = t >> 9, tt = t & 511;
    const u64* X = Bf + m * 4096; const u64* Y = X + 2048;
    u64* O = A + m * 4096;
    int d = tt * 8;
    int i = mp_search(X, 2048, Y, 2048, d), j = d - i;
    #pragma unroll
    for (int k = 0; k < 8; ++k) {
      bool tx = (i < 2048) && (j >= 2048 || X[i] >= Y[j]);
      O[d + k] = tx ? X[i++] : Y[j++];
    }
  }
  __syncthreads();
  {
    const u64* X = A; const u64* Y = A + 4096;
    int d = mhalf * 3000 + t * 3;
    if (t < 1000) {
      int i = mp_search(X, 4096, Y, 4096, d), j = d - i;
      #pragma unroll
      for (int k = 0; k < 3; ++k) {
        bool tx = (i < 4096) && (j >= 4096 || X[i] >= Y[j]);
        u64 key = tx ? X[i++] : Y[j++];
        u32 idx = ~(u32)key;
        const float4 a  = ((const float4*)anchors)[(size_t)b * NANCH + idx];
        const float4 dr = ((const float4*)bbox)[(size_t)b * NANCH + idx];
        float d0 = __fmul_rn(dr.x, 0.1f), d1 = __fmul_rn(dr.y, 0.1f);
        float d2 = __fmul_rn(dr.z, 0.2f), d3 = __fmul_rn(dr.w, 0.2f);
        float h = __fsub_rn(a.z, a.x);
        float w = __fsub_rn(a.w, a.y);
        float cy = __fadd_rn(a.x, __fmul_rn(0.5f, h));
        float cx = __fadd_rn(a.y, __fmul_rn(0.5f, w));
        cy = __fadd_rn(cy, __fmul_rn(d0, h));
        cx = __fadd_rn(cx, __fmul_rn(d1, w));
        h = __fmul_rn(h, (float)exp((double)d2));
        w = __fmul_rn(w, (float)exp((double)d3));
        float y1 = __fsub_rn(cy, __fmul_rn(0.5f, h));
        float x1 = __fsub_rn(cx, __fmul_rn(0.5f, w));
        float4 o; o.x = y1; o.y = x1; o.z = __fadd_rn(y1, h); o.w = __fadd_rn(x1, w);
        boxes[(size_t)b * KPRE + d + k] = o;
      }
    }
  }
}

// ---- 5: suppression bitmask (R8 structure): 256 rows/tile, WBT words/tile, 256 threads,
// 2 rows/thread, WBT/2 words per half. EDGES=true: emit sparse edges, no M writes.
// EDGES=false: dense M (WBT=8 -> full 64B line stores), early-exit on done. ----
template<int WBT, int TNRB, int TNCH, int TNTILE, bool EDGES>
__global__ __launch_bounds__(256) void k_mask_t(const float4* __restrict__ boxes, u64* __restrict__ M,
                                                u32* __restrict__ elist, int* __restrict__ ecnt,
                                                const int* __restrict__ done) {
  if (!EDGES && done[blockIdx.y]) return;
  const double MD = (double)0.7f + 0x1.0p-25;
  const float CHI = 0.700001f, CLO = 0.699999f;
  const int HWB = WBT / 2;  // words per half
  __shared__ float4 sb[WBT * 64];
  __shared__ float  sa[WBT * 64];
  int b = blockIdx.y;
  int tile = TNTILE - 1 - blockIdx.x;  // heavy tiles dispatched first
  int ch = 0, base = 0;
  #pragma unroll
  for (int j = 0; j < TNCH; ++j) {
    int n = (j + 1) * (WBT / 4); if (n > TNRB) n = TNRB;  // rowblocks with upper-tri work
    if (tile >= base + n) { base += n; ch = j + 1; }
  }
  int rb = tile - base;

  int w0 = ch * WBT;
  int c0 = w0 << 6;
  const float4* bb = boxes + (size_t)b * KPRE;

  for (int t = threadIdx.x; t < WBT * 64; t += 256) {
    int c = c0 + t;
    float4 v; v.x = 0.f; v.y = 0.f; v.z = 0.f; v.w = 0.f;
    if (c < KPRE) v = bb[c];
    sb[t] = v;
    sa[t] = __fmul_rn(__fsub_rn(v.z, v.x), __fsub_rn(v.w, v.y));
  }
  __syncthreads();

  int half = threadIdx.x & 1;
  int r0 = rb * 256 + (threadIdx.x >> 1);
  int r1 = r0 + 128;
  bool v0 = r0 < KPRE, v1 = r1 < KPRE;
  float4 z4; z4.x = 0.f; z4.y = 0.f; z4.z = 0.f; z4.w = 0.f;
  float4 br0 = v0 ? bb[r0] : z4;
  float4 br1 = v1 ? bb[r1] : z4;
  float ar0 = __fmul_rn(__fsub_rn(br0.z, br0.x), __fsub_rn(br0.w, br0.y));
  float ar1 = __fmul_rn(__fsub_rn(br1.z, br1.x), __fsub_rn(br1.w, br1.y));
  int wbase = w0 + HWB * half;

  u64 buf0[HWB], buf1[HWB];
  #pragma unroll
  for (int k = 0; k < HWB; ++k) {
    int w = wbase + k;
    int cbase = w << 6;
    int tb = (w - w0) << 6;
    bool n0 = v0 && (w < MW) && (cbase + 63 > r0);
    bool n1 = v1 && (w < MW) && (cbase + 63 > r1);
    u64 bits0 = 0ull, bits1 = 0ull;
    if (n0 | n1) {
      u64 amb0 = 0ull, amb1 = 0ull;
      #pragma unroll 16
      for (int k2 = 0; k2 < 64; ++k2) {
        float4 bc = sb[tb + k2];
        float ac = sa[tb + k2];
        {
          float iy1 = fmaxf(br0.x, bc.x), ix1 = fmaxf(br0.y, bc.y);
          float iy2 = fminf(br0.z, bc.z), ix2 = fminf(br0.w, bc.w);
          float ih = fmaxf(__fsub_rn(iy2, iy1), 0.f), iw = fmaxf(__fsub_rn(ix2, ix1), 0.f);
          float inter = __fmul_rn(ih, iw);
          float uni = __fsub_rn(__fadd_rn(ar0, ac), inter);
          bool hi = inter >= __fmul_rn(uni, CHI);
          bool lo = inter >= __fmul_rn(uni, CLO);
          if (hi) bits0 |= (1ull << k2);
          if (lo != hi) amb0 |= (1ull << k2);
        }
        {
          float iy1 = fmaxf(br1.x, bc.x), ix1 = fmaxf(br1.y, bc.y);
          float iy2 = fminf(br1.z, bc.z), ix2 = fminf(br1.w, bc.w);
          float ih = fmaxf(__fsub_rn(iy2, iy1), 0.f), iw = fmaxf(__fsub_rn(ix2, ix1), 0.f);
          float inter = __fmul_rn(ih, iw);
          float uni = __fsub_rn(__fadd_rn(ar1, ac), inter);
          bool hi = inter >= __fmul_rn(uni, CHI);
          bool lo = inter >= __fmul_rn(uni, CLO);
          if (hi) bits1 |= (1ull << k2);
          if (lo != hi) amb1 |= (1ull << k2);
        }
      }
      while (amb0) {  // exact f64 fallback for ambiguous-band columns (rare)
        int k2 = (int)__builtin_ctzll(amb0); amb0 &= amb0 - 1;
        float4 bc = sb[tb + k2]; float ac = sa[tb + k2];
        float iy1 = fmaxf(br0.x, bc.x), ix1 = fmaxf(br0.y, bc.y);
        float iy2 = fminf(br0.z, bc.z), ix2 = fminf(br0.w, bc.w);
        float ih = fmaxf(__fsub_rn(iy2, iy1), 0.f), iw = fmaxf(__fsub_rn(ix2, ix1), 0.f);
        float inter = __fmul_rn(ih, iw);
        float uni = __fsub_rn(__fadd_rn(ar0, ac), inter);
        if ((double)inter >= MD * (double)uni) bits0 |= (1ull << k2);
      }
      while (amb1) {
        int k2 = (int)__builtin_ctzll(amb1); amb1 &= amb1 - 1;
        float4 bc = sb[tb + k2]; float ac = sa[tb + k2];
        float iy1 = fmaxf(br1.x, bc.x), ix1 = fmaxf(br1.y, bc.y);
        float iy2 = fminf(br1.z, bc.z), ix2 = fminf(br1.w, bc.w);
        float ih = fmaxf(__fsub_rn(iy2, iy1), 0.f), iw = fmaxf(__fsub_rn(ix2, ix1), 0.f);
        float inter = __fmul_rn(ih, iw);
        float uni = __fsub_rn(__fadd_rn(ar1, ac), inter);
        if ((double)inter >= MD * (double)uni) bits1 |= (1ull << k2);
      }
      if (n0 && cbase <= r0) bits0 &= ~((r0 - cbase >= 63) ? ~0ull : ((1ull << (r0 - cbase + 1)) - 1ull));
      if (n1 && cbase <= r1) bits1 &= ~((r1 - cbase >= 63) ? ~0ull : ((1ull << (r1 - cbase + 1)) - 1ull));
    }
    if (EDGES) {
      // guard with n0/n1: sub-diagonal (c <= r) garbage bits must NOT become edges
      u64 e0 = n0 ? bits0 : 0ull;
      while (e0) {
        int k2 = (int)__builtin_ctzll(e0); e0 &= e0 - 1;
        int pos = atomicAdd(&ecnt[b * 32], 1);
        if (pos < EMAX) elist[(size_t)b * EMAX + pos] = ((u32)r0 << 13) | (u32)(cbase + k2);
      }
      u64 e1 = n1 ? bits1 : 0ull;
      while (e1) {
        int k2 = (int)__builtin_ctzll(e1); e1 &= e1 - 1;
        int pos = atomicAdd(&ecnt[b * 32], 1);
        if (pos < EMAX) elist[(size_t)b * EMAX + pos] = ((u32)r1 << 13) | (u32)(cbase + k2);
      }
    } else {
      buf0[k] = n0 ? bits0 : 0ull;
      buf1[k] = n1 ? bits1 : 0ull;
    }
  }
  if (!EDGES) {
    if (v0) {
      ulonglong2* dst = (ulonglong2*)(M + ((size_t)b * KPRE + r0) * MSTRIDE + wbase);
      #pragma unroll
      for (int k = 0; k < HWB / 2; ++k) {
        ulonglong2 p; p.x = buf0[2 * k]; p.y = buf0[2 * k + 1];
        dst[k] = p;
      }
    }
    if (v1) {
      ulonglong2* dst = (ulonglong2*)(M + ((size_t)b * KPRE + r1) * MSTRIDE + wbase);
      #pragma unroll
      for (int k = 0; k < HWB / 2; ++k) {
        ulonglong2 p; p.x = buf1[2 * k]; p.y = buf1[2 * k + 1];
        dst[k] = p;
      }
    }
  }
}

// ---- 6a: PHASE-1 scan via Jacobi fixpoint on the sparse suppression DAG ----
template<int TMW>  // TMW <= 64, R1 = TMW*64
__global__ __launch_bounds__(64) void k_scan1(const u32* __restrict__ elist, const int* __restrict__ ecnt,
                                              const float4* __restrict__ boxes, float4* __restrict__ out,
                                              int* __restrict__ done) {
  __shared__ u32 se[EMAX];       // 4 KiB
  __shared__ u64 skw[TMW];       // keep words (LDS: exec-safe reads)
  __shared__ u32 su32[TMW * 2];  // suppression accumulator (u32 halves for LDS atomicOr)
  __shared__ int pfx[TMW];
  __shared__ int s_tot;
  int b = blockIdx.x;
  int lane = threadIdx.x;  // 0..63
  int E = ecnt[b * 32];
  if (E > EMAX) return;  // overflow -> fallback

  for (int i = lane; i < E; i += 64) se[i] = elist[(size_t)b * EMAX + i];
  u64 kw = (lane < TMW) ? ~0ull : 0ull;
  if (lane < TMW) skw[lane] = kw;
  bool conv = false;
  __syncthreads();

  for (int iter = 0; iter < 64 && !conv; ++iter) {
    for (int i = lane; i < TMW * 2; i += 64) su32[i] = 0u;
    __syncthreads();
    for (int i = lane; i < E; i += 64) {
      u32 v = se[i];
      int r = (int)(v >> 13), c = (int)(v & 8191u);
      if ((skw[r >> 6] >> (r & 63)) & 1ull)
        atomicOr(&su32[c >> 5], 1u << (c & 31));
    }
    __syncthreads();
    u64 nkw = kw;
    if (lane < TMW)
      nkw = ~((u64)su32[2 * lane] | ((u64)su32[2 * lane + 1] << 32));
    u64 chg = __ballot(nkw != kw);
    kw = nkw;
    if (lane < TMW) skw[lane] = kw;  // no cross-lane skw reads until after next barrier
    if (chg == 0ull) conv = true;
    __syncthreads();
  }
  if (!conv) return;  // no certified fixpoint -> fallback (done stays 0)

  if (lane == 0) {
    int s = 0;
    for (int t = 0; t < TMW; ++t) { pfx[t] = s; s += (int)__popcll(skw[t]); }
    s_tot = s;
  }
  __syncthreads();

  if (s_tot < PROP) return;  // not enough keeps within R1 -> fallback (done stays 0)
  if (lane == 0) done[b] = 1;

  const float4* bb = boxes + (size_t)b * KPRE;
  float4* ob = out + (size_t)b * PROP;
  if (lane < TMW) {
    u64 bits = kw;
    int slot = pfx[lane];
    while (bits && slot < PROP) {
      int k = (int)__builtin_ctzll(bits);
      ob[slot] = bb[(lane << 6) + k];
      ++slot;
      bits &= bits - 1;
    }
  }
}

// ---- 6b: PHASE-2 fallback scan (proven R12 4-wave depth-1 pipeline), early-exits on done ----
template<int TMW>
__global__ __launch_bounds__(256) void k_scan_t(const u64* __restrict__ M, const float4* __restrict__ boxes,
                                                float4* __restrict__ out, int* __restrict__ done) {
  if (done[blockIdx.x]) return;
  __shared__ u64 xch[2][4];
  __shared__ u64 fin[TMW];
  __shared__ int pfx[TMW];
  __shared__ int s_tot;
  const int NL = (TMW + 1) / 2;  // lanes holding keep-words (2 per lane)
  int b = blockIdx.x;
  int tid = threadIdx.x;
  int lane = tid & 63;
  int wv = tid >> 6;
  const u64* Mb = M + (size_t)b * KPRE * MSTRIDE;

  if (tid < TMW) fin[tid] = 0ull;

  u64 kw0 = ~0ull, kw1 = ~0ull;
  u64 cur = ~0ull;
  u64 dw = Mb[(size_t)lane * MSTRIDE + 0];
  int count = 0;
  ulonglong2 mmA[16], mmB[16];

  {
    bool la = (lane < NL);
    #pragma unroll
    for (int kk = 0; kk < 16; ++kk) {
      int r = wv + (kk << 2);
      ulonglong2 t2; t2.x = 0ull; t2.y = 0ull;
      if (la && r < KPRE) t2 = ((const ulonglong2*)(Mb + (size_t)r * MSTRIDE))[lane];
      mmA[kk] = t2;
    }
  }

#define SCAN_BODY(MMCUR, MMNXT)                                                         \
  {                                                                                     \
    int rem = KPRE - (w << 6);                                                          \
    u64 valid = (rem >= 64) ? ~0ull : ((1ull << rem) - 1ull);                           \
    cur &= valid;                                                                       \
    u64 nz = __ballot(dw != 0ull);                                                      \
    u64 pend = cur & nz;                                                                \
    while (pend) {                                                                      \
      int k = (int)__builtin_ctzll(pend);                                               \
      u64 d = bcast64(dw, k);                                                           \
      cur &= ~d;                                                                        \
      pend &= (pend - 1);                                                               \
      pend &= cur;                                                                      \
    }                                                                                   \
    if (tid == 0) fin[w] = cur;                                                         \
    count += (int)__popcll(cur);                                                        \
    if (count >= PROP || w == TMW - 1) break;                                           \
    {                                                                                   \
      int rn = ((w + 1) << 6) + lane;                                                   \
      dw = (rn < KPRE) ? Mb[(size_t)rn * MSTRIDE + (w + 1)] : 0ull;                     \
    }                                                                                   \
    {                                                                                   \
      bool la = (lane < NL) && (2 * lane + 1 >= w + 2);                                 \
      _Pragma("unroll")                                                                 \
      for (int kk = 0; kk < 16; ++kk) {                                                 \
        int r = ((w + 1) << 6) + wv + (kk << 2);                                        \
        ulonglong2 t2; t2.x = 0ull; t2.y = 0ull;                                        \
        if (la && r < KPRE) t2 = ((const ulonglong2*)(Mb + (size_t)r * MSTRIDE))[lane]; \
        MMNXT[kk] = t2;                                                                 \
      }                                                                                 \
    }                                                                                   \
    _Pragma("unroll")                                                                   \
    for (int kk = 0; kk < 16; ++kk) {                                                   \
      int k = wv + (kk << 2);                                                           \
      u64 sel = 0ull - ((cur >> k) & 1ull);                                             \
      kw0 &= ~(MMCUR[kk].x & sel);                                                      \
      kw1 &= ~(MMCUR[kk].y & sel);                                                      \
    }                                                                                   \
    int nw = w + 1;                                                                     \
    if (lane == (nw >> 1)) xch[nw & 1][wv] = (nw & 1) ? kw1 : kw0;                      \
    asm volatile("s_waitcnt lgkmcnt(0)" ::: "memory");                                  \
    __builtin_amdgcn_sched_barrier(0);                                                  \
    __builtin_amdgcn_s_barrier();                                                      \
    __builtin_amdgcn_sched_barrier(0);                                                  \
    cur = xch[nw & 1][0] & xch[nw & 1][1] & xch[nw & 1][2] & xch[nw & 1][3];            \
  }

  for (int w = 0; w < TMW; ++w) {
    if ((w & 1) == 0) SCAN_BODY(mmA, mmB)
    else              SCAN_BODY(mmB, mmA)
  }
#undef SCAN_BODY
  __syncthreads();

  if (tid == 0) {
    int s = 0;
    for (int t = 0; t < TMW; ++t) { pfx[t] = s; s += (int)__popcll(fin[t]); }
    s_tot = (s < PROP) ? s : PROP;
  }
  __syncthreads();

  const float4* bb = boxes + (size_t)b * KPRE;
  float4* ob = out + (size_t)b * PROP;
  if (tid < TMW) {
    u64 bits = fin[tid];
    int slot = pfx[tid];
    while (bits && slot < PROP) {
      int k = (int)__builtin_ctzll(bits);
      ob[slot] = bb[(tid << 6) + k];
      ++slot;
      bits &= bits - 1;
    }
  }
  {
    float4 z; z.x = 0.f; z.y = 0.f; z.z = 0.f; z.w = 0.f;
    for (int i = s_tot + tid; i < PROP; i += 256) ob[i] = z;
  }
}

extern "C" void kernel_launch(void* const* d_in, const int* in_sizes, int n_in,
                              void* d_out, int out_size, void* d_ws, size_t ws_size,
                              hipStream_t stream) {
  const float* probs   = (const float*)d_in[0];
  const float* bbox    = (const float*)d_in[1];
  const float* anchors = (const float*)d_in[2];
  char* ws = (char*)d_ws;
  u32* coarse  = (u32*)(ws + OFF_COARSE);        // u32[8][HB][256], fully overwritten
  int* meta    = (int*)(ws + OFF_META);          // T[8]
  int* cnt     = (int*)(ws + OFF_META + 4096);   // cnt[b*32], 128B-padded
  int* done    = (int*)(ws + OFF_META + 16384);  // done[8]
  int* ecnt    = (int*)(ws + OFF_META + 16512);  // ecnt[b*32], 128B-padded
  u32* elist   = (u32*)(ws + OFF_META + 20480);  // u32[8][EMAX] = 32 KB
  u64* cand    = (u64*)(ws + OFF_CAND);
  float4* boxes = (float4*)(ws + OFF_BOXES);
  u64* M       = (u64*)(ws + OFF_M);
  u16* histr   = (u16*)(ws + OFF_M);             // reuse M region (dead until k_mask)
  float4* out  = (float4*)d_out;

  // no hipMemsetAsync: coarse is fully overwritten by k_hist; cnt/ecnt/done zeroed by k_thresh.

  dim3 gh(HB, BATCH);
  k_hist<<<gh, 1024, 0, stream>>>(probs, histr, coarse);
  k_thresh<<<BATCH, 256, 0, stream>>>(histr, coarse, meta, cnt, ecnt, done);
  dim3 gc((NANCH / 2 + 255) / 256, BATCH);
  k_compact<<<gc, 256, 0, stream>>>(probs, meta, cnt, cand);
  dim3 gl(8, BATCH);
  k_lsort<<<gl, 1024, 0, stream>>>(cand, cnt);
  dim3 gmr(2, BATCH);
  k_merge<<<gmr, 1024, 0, stream>>>(cand, anchors, bbox, boxes);

  // phase 1: 4-word x 256-row tiles (55/batch, 440 blocks) -> ~1.7 waves/SIMD, same staging
  dim3 g1(NTILE1, BATCH);
  k_mask_t<4, R1 / 256, MW1 / 4, NTILE1, true><<<g1, 256, 0, stream>>>(boxes, M, elist, ecnt, done);
  k_scan1<MW1><<<BATCH, 64, 0, stream>>>(elist, ecnt, boxes, out, done);

  // phase 2: exact fallback (8-word tiles; early-exits per batch when done)
  dim3 g2(NTILE, BATCH);
  k_mask_t<8, 24, 12, NTILE, false><<<g2, 256, 0, stream>>>(boxes, M, elist, ecnt, done);
  k_scan_t<MW><<<BATCH, 256, 0, stream>>>(M, boxes, out, done);
}

// Round 25
// 113.200 us; speedup vs baseline: 1.1678x; 1.0001x over previous
//
#include <hip/hip_runtime.h>
#include <hip/hip_bf16.h>

#define BATCH 8
#define NANCH 261888
#define KPRE 6000
#define PROP 2000
#define CAP 8192
#define NBUCKET 32768
#define MW 94       // u64 words per row actually used (94*64 = 6016 >= 6000)
#define MSTRIDE 96  // padded stride in u64 words; rows are 768B, 64B-aligned
#define NTILE 156   // phase-2 grid per batch (8-word tiles): sum_{ch=0..11} min(24, 2ch+2)
#define R1 2560     // speculative NMS truncation bound (40 words)
#define MW1 40
#define NTILE1 55   // phase-1 (4-word tiles, 256 rows): sum_{ch=0..9} min(10, ch+1)
#define HB 32       // histogram blocks per batch (fill all 256 CUs)
#define EMAX 1024   // phase-1 edge-list capacity per batch (expected ~100)

typedef unsigned int u32;
typedef unsigned long long u64;
typedef unsigned short u16;

// ---- workspace layout (bytes) ----
#define OFF_COARSE 0ull         // u32[8][HB][256] = 256 KB, fully overwritten by k_hist
#define OFF_META (1ull << 20)   // +0: T[8]; +4096: cnt[b*32]; +16384: done[8];
                                // +16512: ecnt[b*32]; +20480: elist u32[8][EMAX]
#define OFF_CAND (OFF_META + 65536ull)                      // B*CAP*8 = 512 KiB
#define OFF_BOXES (OFF_CAND + (unsigned long long)BATCH * CAP * 8ull)
#define OFF_M ((OFF_BOXES + (unsigned long long)BATCH * KPRE * 16ull + 255ull) & ~255ull)
// hist u16 rows (16 MB, HB=32) live in the M region (36.9 MB, dead until k_mask).

// broadcast lane srclane's 64-bit value to all lanes; srclane must be wave-uniform
// (v_readlane: ignores EXEC, safe under divergence)
__device__ inline u64 bcast64(u64 v, int srclane) {
  int lo = __builtin_amdgcn_readlane((int)(u32)v, srclane);
  int hi = __builtin_amdgcn_readlane((int)(v >> 32), srclane);
  return ((u64)(u32)hi << 32) | (u32)lo;
}

// ---- 1: per-block private LDS histogram; flush u16 row + per-block coarse row (no atomics) ----
__global__ __launch_bounds__(1024) void k_hist(const float* __restrict__ probs, u16* __restrict__ histr,
                                               u32* __restrict__ coarse) {
  __shared__ u32 sh[NBUCKET];  // 128 KiB
  int b = blockIdx.y, blk = blockIdx.x;
  for (int t = threadIdx.x; t < NBUCKET; t += 1024) sh[t] = 0;
  __syncthreads();
  const float4* p4 = (const float4*)(probs + (size_t)b * NANCH * 2);
  const int n4 = NANCH / 2;  // 2 scores per float4
  for (int i = blk * 1024 + threadIdx.x; i < n4; i += HB * 1024) {
    float4 v = p4[i];
    atomicAdd(&sh[__float_as_uint(v.y) >> 15], 1u);
    atomicAdd(&sh[__float_as_uint(v.w) >> 15], 1u);
  }
  __syncthreads();
  u32* dst = (u32*)(histr + ((size_t)b * HB + blk) * NBUCKET);
  for (int t = threadIdx.x; t < NBUCKET / 2; t += 1024)
    dst[t] = (sh[2 * t] & 0xFFFFu) | (sh[2 * t + 1] << 16);
  // per-block coarse 256-bin row: full overwrite (no zero-init, no atomics)
  if (threadIdx.x < 256) {
    int t = threadIdx.x;
    u32 s = 0;
    #pragma unroll 8
    for (int i = 0; i < 128; ++i) s += sh[128 * t + ((i + t) & 127)];
    coarse[((size_t)b * HB + blk) * 256 + t] = s;
  }
}

// ---- 2: find threshold bucket T (sum per-block coarse rows) + zero cnt/ecnt/done ----
__global__ __launch_bounds__(256) void k_thresh(const u16* __restrict__ histr, const u32* __restrict__ coarse,
                                                int* __restrict__ meta, int* __restrict__ cnt,
                                                int* __restrict__ ecnt, int* __restrict__ done) {
  __shared__ u32 cg[256];
  __shared__ int bt[128];
  __shared__ int s_c, s_sfx;
  int b = blockIdx.x;
  int t = threadIdx.x;
  {
    u32 s = 0;
    for (int r = 0; r < HB; ++r) s += coarse[((size_t)b * HB + r) * 256 + t];
    cg[t] = s;
  }
  if (t == 1) { cnt[b * 32] = 0; ecnt[b * 32] = 0; done[b] = 0; }  // pre-k_compact zeroing
  __syncthreads();
  if (t == 0) {
    int suffix = 0, c = 0;
    for (int cc = 255; cc >= 0; --cc) {
      int ns = suffix + (int)cg[cc];
      if (ns >= KPRE) { c = cc; break; }
      suffix = ns;
    }
    s_c = c; s_sfx = suffix;
  }
  __syncthreads();
  int cstar = s_c;
  if (t < 128) {
    const u16* hb = histr + (size_t)b * HB * NBUCKET;
    int bsum = 0;
    for (int r = 0; r < HB; ++r) bsum += hb[(size_t)r * NBUCKET + cstar * 128 + t];
    bt[t] = bsum;
  }
  __syncthreads();
  if (t == 0) {
    int run = s_sfx, T = 0;
    for (int k = 127; k >= 0; --k) {
      run += bt[k];
      if (run >= KPRE) { T = cstar * 128 + k; break; }
    }
    meta[b] = T;
  }
}

// ---- 3: compact candidates (bucket >= T); ballot -> LDS -> 1 global atomic/block ----
__global__ __launch_bounds__(256) void k_compact(const float* __restrict__ probs, const int* __restrict__ meta,
                                                 int* __restrict__ cnt, u64* __restrict__ cand) {
  __shared__ int wbase[4];
  __shared__ int btot, bbase;
  int b = blockIdx.y;
  int T = meta[b];
  const int n4 = NANCH / 2;
  int i = blockIdx.x * 256 + threadIdx.x;
  int lane = threadIdx.x & 63, wv = threadIdx.x >> 6;
  if (threadIdx.x == 0) btot = 0;
  __syncthreads();
  u32 bits0 = 0, bits1 = 0;
  bool p0 = false, p1 = false;
  if (i < n4) {
    float4 v = ((const float4*)(probs + (size_t)b * NANCH * 2))[i];
    bits0 = __float_as_uint(v.y); bits1 = __float_as_uint(v.w);
    p0 = (int)(bits0 >> 15) >= T; p1 = (int)(bits1 >> 15) >= T;
  }
  u64 m0 = __ballot(p0);
  u64 m1 = __ballot(p1);
  int c0 = (int)__popcll(m0), c1 = (int)__popcll(m1);
  if (lane == 0) wbase[wv] = (c0 + c1) ? atomicAdd(&btot, c0 + c1) : 0;
  __syncthreads();
  if (threadIdx.x == 0 && btot) bbase = atomicAdd(&cnt[b * 32], btot);
  __syncthreads();
  if (p0 | p1) {
    int base = bbase + wbase[wv];
    if (p0) {
      int pos = base + (int)__popcll(m0 & ((1ull << lane) - 1ull));
      if (pos < CAP) cand[(size_t)b * CAP + pos] = ((u64)bits0 << 32) | (u32)(~(u32)(2 * i));
    }
    if (p1) {
      int pos = base + c0 + (int)__popcll(m1 & ((1ull << lane) - 1ull));
      if (pos < CAP) cand[(size_t)b * CAP + pos] = ((u64)bits1 << 32) | (u32)(~(u32)(2 * i + 1));
    }
  }
}

// ---- 4a: local bitonic sort of 1024-element runs (desc), 8 runs per batch ----
__global__ __launch_bounds__(1024) void k_lsort(u64* __restrict__ cand, const int* __restrict__ cnt) {
  __shared__ u64 sk[1024];  // 8 KiB
  int b = blockIdx.y, run = blockIdx.x;
  int C = cnt[b * 32];
  int g = run * 1024 + threadIdx.x;
  sk[threadIdx.x] = (g < C) ? cand[(size_t)b * CAP + g] : 0ull;
  __syncthreads();
  for (int ksz = 2; ksz <= 1024; ksz <<= 1) {
    for (int j = ksz >> 1; j > 0; j >>= 1) {
      int i = threadIdx.x;
      int ixj = i ^ j;
      if (ixj > i) {
        u64 a = sk[i], c2 = sk[ixj];
        bool up = (i & ksz) == 0;
        if ((a < c2) == up) { sk[i] = c2; sk[ixj] = a; }  // descending
      }
      __syncthreads();
    }
  }
  cand[(size_t)b * CAP + g] = sk[threadIdx.x];
}

// merge-path partition for DESCENDING keys, stable toward X (uses >=)
__device__ inline int mp_search(const u64* X, int n1, const u64* Y, int n2, int d) {
  int lo = d - n2; if (lo < 0) lo = 0;
  int hi = d < n1 ? d : n1;
  while (lo < hi) {
    int m = (lo + hi) >> 1;
    if (X[m] >= Y[d - 1 - m]) lo = m + 1; else hi = m;
  }
  return lo;
}

// ---- 4b: merge 8 sorted 1024-runs -> top-6000, fused gather + box decode ----
__global__ __launch_bounds__(1024) void k_merge(const u64* __restrict__ cand,
                                                const float* __restrict__ anchors, const float* __restrict__ bbox,
                                                float4* __restrict__ boxes) {
  __shared__ u64 A[CAP];   // 64 KiB
  __shared__ u64 Bf[CAP];  // 64 KiB
  int b = blockIdx.y;
  int mhalf = blockIdx.x;
  int t = threadIdx.x;
  for (int r = t; r < CAP; r += 1024) A[r] = cand[(size_t)b * CAP + r];
  __syncthreads();
  {
    int m = t >> 8, tt = t & 255;
    const u64* X = A + m * 2048; const u64* Y = X + 1024;
    u64* O = Bf + m * 2048;
    int d = tt * 8;
    int i = mp_search(X, 1024, Y, 1024, d), j = d - i;
    #pragma unroll
    for (int k = 0; k < 8; ++k) {
      bool tx = (i < 1024) && (j >= 1024 || X[i] >= Y[j]);
      O[d + k] = tx ? X[i++] : Y[j++];
    }
  }
  __syncthreads();
  {
    int m = t >> 9, tt = t & 511;
    const u64* X = Bf + m * 4096; const u64* Y = X + 2048;
    u64* O = A + m * 4096;
    int d = tt * 8;
    int i = mp_search(X, 2048, Y, 2048, d), j = d - i;
    #pragma unroll
    for (int k = 0; k < 8; ++k) {
      bool tx = (i < 2048) && (j >= 2048 || X[i] >= Y[j]);
      O[d + k] = tx ? X[i++] : Y[j++];
    }
  }
  __syncthreads();
  {
    const u64* X = A; const u64* Y = A + 4096;
    int d = mhalf * 3000 + t * 3;
    if (t < 1000) {
      int i = mp_search(X, 4096, Y, 4096, d), j = d - i;
      #pragma unroll
      for (int k = 0; k < 3; ++k) {
        bool tx = (i < 4096) && (j >= 4096 || X[i] >= Y[j]);
        u64 key = tx ? X[i++] : Y[j++];
        u32 idx = ~(u32)key;
        const float4 a  = ((const float4*)anchors)[(size_t)b * NANCH + idx];
        const float4 dr = ((const float4*)bbox)[(size_t)b * NANCH + idx];
        float d0 = __fmul_rn(dr.x, 0.1f), d1 = __fmul_rn(dr.y, 0.1f);
        float d2 = __fmul_rn(dr.z, 0.2f), d3 = __fmul_rn(dr.w, 0.2f);
        float h = __fsub_rn(a.z, a.x);
        float w = __fsub_rn(a.w, a.y);
        float cy = __fadd_rn(a.x, __fmul_rn(0.5f, h));
        float cx = __fadd_rn(a.y, __fmul_rn(0.5f, w));
        cy = __fadd_rn(cy, __fmul_rn(d0, h));
        cx = __fadd_rn(cx, __fmul_rn(d1, w));
        h = __fmul_rn(h, (float)exp((double)d2));
        w = __fmul_rn(w, (float)exp((double)d3));
        float y1 = __fsub_rn(cy, __fmul_rn(0.5f, h));
        float x1 = __fsub_rn(cx, __fmul_rn(0.5f, w));
        float4 o; o.x = y1; o.y = x1; o.z = __fadd_rn(y1, h); o.w = __fadd_rn(x1, w);
        boxes[(size_t)b * KPRE + d + k] = o;
      }
    }
  }
}

// ---- 5: suppression bitmask (R8 structure): 256 rows/tile, WBT words/tile, 256 threads,
// 2 rows/thread, WBT/2 words per half. EDGES=true: emit sparse edges, no M writes.
// EDGES=false: dense M (WBT=8 -> full 64B line stores), early-exit on done. ----
template<int WBT, int TNRB, int TNCH, int TNTILE, bool EDGES>
__global__ __launch_bounds__(256) void k_mask_t(const float4* __restrict__ boxes, u64* __restrict__ M,
                                                u32* __restrict__ elist, int* __restrict__ ecnt,
                                                const int* __restrict__ done) {
  if (!EDGES && done[blockIdx.y]) return;
  const double MD = (double)0.7f + 0x1.0p-25;
  const float CHI = 0.700001f, CLO = 0.699999f;
  const int HWB = WBT / 2;  // words per half
  __shared__ float4 sb[WBT * 64];
  __shared__ float  sa[WBT * 64];
  int b = blockIdx.y;
  int tile = TNTILE - 1 - blockIdx.x;  // heavy tiles dispatched first
  int ch = 0, base = 0;
  #pragma unroll
  for (int j = 0; j < TNCH; ++j) {
    int n = (j + 1) * (WBT / 4); if (n > TNRB) n = TNRB;  // rowblocks with upper-tri work
    if (tile >= base + n) { base += n; ch = j + 1; }
  }
  int rb = tile - base;

  int w0 = ch * WBT;
  int c0 = w0 << 6;
  const float4* bb = boxes + (size_t)b * KPRE;

  for (int t = threadIdx.x; t < WBT * 64; t += 256) {
    int c = c0 + t;
    float4 v; v.x = 0.f; v.y = 0.f; v.z = 0.f; v.w = 0.f;
    if (c < KPRE) v = bb[c];
    sb[t] = v;
    sa[t] = __fmul_rn(__fsub_rn(v.z, v.x), __fsub_rn(v.w, v.y));
  }
  __syncthreads();

  int half = threadIdx.x & 1;
  int r0 = rb * 256 + (threadIdx.x >> 1);
  int r1 = r0 + 128;
  bool v0 = r0 < KPRE, v1 = r1 < KPRE;
  float4 z4; z4.x = 0.f; z4.y = 0.f; z4.z = 0.f; z4.w = 0.f;
  float4 br0 = v0 ? bb[r0] : z4;
  float4 br1 = v1 ? bb[r1] : z4;
  float ar0 = __fmul_rn(__fsub_rn(br0.z, br0.x), __fsub_rn(br0.w, br0.y));
  float ar1 = __fmul_rn(__fsub_rn(br1.z, br1.x), __fsub_rn(br1.w, br1.y));
  int wbase = w0 + HWB * half;

  u64 buf0[HWB], buf1[HWB];
  #pragma unroll
  for (int k = 0; k < HWB; ++k) {
    int w = wbase + k;
    int cbase = w << 6;
    int tb = (w - w0) << 6;
    bool n0 = v0 && (w < MW) && (cbase + 63 > r0);
    bool n1 = v1 && (w < MW) && (cbase + 63 > r1);
    u64 bits0 = 0ull, bits1 = 0ull;
    if (n0 | n1) {
      u64 amb0 = 0ull, amb1 = 0ull;
      #pragma unroll 16
      for (int k2 = 0; k2 < 64; ++k2) {
        float4 bc = sb[tb + k2];
        float ac = sa[tb + k2];
        {
          float iy1 = fmaxf(br0.x, bc.x), ix1 = fmaxf(br0.y, bc.y);
          float iy2 = fminf(br0.z, bc.z), ix2 = fminf(br0.w, bc.w);
          float ih = fmaxf(__fsub_rn(iy2, iy1), 0.f), iw = fmaxf(__fsub_rn(ix2, ix1), 0.f);
          float inter = __fmul_rn(ih, iw);
          float uni = __fsub_rn(__fadd_rn(ar0, ac), inter);
          bool hi = inter >= __fmul_rn(uni, CHI);
          bool lo = inter >= __fmul_rn(uni, CLO);
          if (hi) bits0 |= (1ull << k2);
          if (lo != hi) amb0 |= (1ull << k2);
        }
        {
          float iy1 = fmaxf(br1.x, bc.x), ix1 = fmaxf(br1.y, bc.y);
          float iy2 = fminf(br1.z, bc.z), ix2 = fminf(br1.w, bc.w);
          float ih = fmaxf(__fsub_rn(iy2, iy1), 0.f), iw = fmaxf(__fsub_rn(ix2, ix1), 0.f);
          float inter = __fmul_rn(ih, iw);
          float uni = __fsub_rn(__fadd_rn(ar1, ac), inter);
          bool hi = inter >= __fmul_rn(uni, CHI);
          bool lo = inter >= __fmul_rn(uni, CLO);
          if (hi) bits1 |= (1ull << k2);
          if (lo != hi) amb1 |= (1ull << k2);
        }
      }
      while (amb0) {  // exact f64 fallback for ambiguous-band columns (rare)
        int k2 = (int)__builtin_ctzll(amb0); amb0 &= amb0 - 1;
        float4 bc = sb[tb + k2]; float ac = sa[tb + k2];
        float iy1 = fmaxf(br0.x, bc.x), ix1 = fmaxf(br0.y, bc.y);
        float iy2 = fminf(br0.z, bc.z), ix2 = fminf(br0.w, bc.w);
        float ih = fmaxf(__fsub_rn(iy2, iy1), 0.f), iw = fmaxf(__fsub_rn(ix2, ix1), 0.f);
        float inter = __fmul_rn(ih, iw);
        float uni = __fsub_rn(__fadd_rn(ar0, ac), inter);
        if ((double)inter >= MD * (double)uni) bits0 |= (1ull << k2);
      }
      while (amb1) {
        int k2 = (int)__builtin_ctzll(amb1); amb1 &= amb1 - 1;
        float4 bc = sb[tb + k2]; float ac = sa[tb + k2];
        float iy1 = fmaxf(br1.x, bc.x), ix1 = fmaxf(br1.y, bc.y);
        float iy2 = fminf(br1.z, bc.z), ix2 = fminf(br1.w, bc.w);
        float ih = fmaxf(__fsub_rn(iy2, iy1), 0.f), iw = fmaxf(__fsub_rn(ix2, ix1), 0.f);
        float inter = __fmul_rn(ih, iw);
        float uni = __fsub_rn(__fadd_rn(ar1, ac), inter);
        if ((double)inter >= MD * (double)uni) bits1 |= (1ull << k2);
      }
      if (n0 && cbase <= r0) bits0 &= ~((r0 - cbase >= 63) ? ~0ull : ((1ull << (r0 - cbase + 1)) - 1ull));
      if (n1 && cbase <= r1) bits1 &= ~((r1 - cbase >= 63) ? ~0ull : ((1ull << (r1 - cbase + 1)) - 1ull));
    }
    if (EDGES) {
      // guard with n0/n1: sub-diagonal (c <= r) garbage bits must NOT become edges
      u64 e0 = n0 ? bits0 : 0ull;
      while (e0) {
        int k2 = (int)__builtin_ctzll(e0); e0 &= e0 - 1;
        int pos = atomicAdd(&ecnt[b * 32], 1);
        if (pos < EMAX) elist[(size_t)b * EMAX + pos] = ((u32)r0 << 13) | (u32)(cbase + k2);
      }
      u64 e1 = n1 ? bits1 : 0ull;
      while (e1) {
        int k2 = (int)__builtin_ctzll(e1); e1 &= e1 - 1;
        int pos = atomicAdd(&ecnt[b * 32], 1);
        if (pos < EMAX) elist[(size_t)b * EMAX + pos] = ((u32)r1 << 13) | (u32)(cbase + k2);
      }
    } else {
      buf0[k] = n0 ? bits0 : 0ull;
      buf1[k] = n1 ? bits1 : 0ull;
    }
  }
  if (!EDGES) {
    if (v0) {
      ulonglong2* dst = (ulonglong2*)(M + ((size_t)b * KPRE + r0) * MSTRIDE + wbase);
      #pragma unroll
      for (int k = 0; k < HWB / 2; ++k) {
        ulonglong2 p; p.x = buf0[2 * k]; p.y = buf0[2 * k + 1];
        dst[k] = p;
      }
    }
    if (v1) {
      ulonglong2* dst = (ulonglong2*)(M + ((size_t)b * KPRE + r1) * MSTRIDE + wbase);
      #pragma unroll
      for (int k = 0; k < HWB / 2; ++k) {
        ulonglong2 p; p.x = buf1[2 * k]; p.y = buf1[2 * k + 1];
        dst[k] = p;
      }
    }
  }
}

// ---- 6a: PHASE-1 scan via Jacobi fixpoint on the sparse suppression DAG ----
template<int TMW>  // TMW <= 64, R1 = TMW*64
__global__ __launch_bounds__(64) void k_scan1(const u32* __restrict__ elist, const int* __restrict__ ecnt,
                                              const float4* __restrict__ boxes, float4* __restrict__ out,
                                              int* __restrict__ done) {
  __shared__ u32 se[EMAX];       // 4 KiB
  __shared__ u64 skw[TMW];       // keep words (LDS: exec-safe reads)
  __shared__ u32 su32[TMW * 2];  // suppression accumulator (u32 halves for LDS atomicOr)
  __shared__ int pfx[TMW];
  __shared__ int s_tot;
  int b = blockIdx.x;
  int lane = threadIdx.x;  // 0..63
  int E = ecnt[b * 32];
  if (E > EMAX) return;  // overflow -> fallback

  for (int i = lane; i < E; i += 64) se[i] = elist[(size_t)b * EMAX + i];
  u64 kw = (lane < TMW) ? ~0ull : 0ull;
  if (lane < TMW) skw[lane] = kw;
  bool conv = false;
  __syncthreads();

  for (int iter = 0; iter < 64 && !conv; ++iter) {
    for (int i = lane; i < TMW * 2; i += 64) su32[i] = 0u;
    __syncthreads();
    for (int i = lane; i < E; i += 64) {
      u32 v = se[i];
      int r = (int)(v >> 13), c = (int)(v & 8191u);
      if ((skw[r >> 6] >> (r & 63)) & 1ull)
        atomicOr(&su32[c >> 5], 1u << (c & 31));
    }
    __syncthreads();
    u64 nkw = kw;
    if (lane < TMW)
      nkw = ~((u64)su32[2 * lane] | ((u64)su32[2 * lane + 1] << 32));
    u64 chg = __ballot(nkw != kw);
    kw = nkw;
    if (lane < TMW) skw[lane] = kw;  // no cross-lane skw reads until after next barrier
    if (chg == 0ull) conv = true;
    __syncthreads();
  }
  if (!conv) return;  // no certified fixpoint -> fallback (done stays 0)

  if (lane == 0) {
    int s = 0;
    for (int t = 0; t < TMW; ++t) { pfx[t] = s; s += (int)__popcll(skw[t]); }
    s_tot = s;
  }
  __syncthreads();

  if (s_tot < PROP) return;  // not enough keeps within R1 -> fallback (done stays 0)
  if (lane == 0) done[b] = 1;

  const float4* bb = boxes + (size_t)b * KPRE;
  float4* ob = out + (size_t)b * PROP;
  if (lane < TMW) {
    u64 bits = kw;
    int slot = pfx[lane];
    while (bits && slot < PROP) {
      int k = (int)__builtin_ctzll(bits);
      ob[slot] = bb[(lane << 6) + k];
      ++slot;
      bits &= bits - 1;
    }
  }
}

// ---- 6b: PHASE-2 fallback scan (proven R12 4-wave depth-1 pipeline), early-exits on done ----
template<int TMW>
__global__ __launch_bounds__(256) void k_scan_t(const u64* __restrict__ M, const float4* __restrict__ boxes,
                                                float4* __restrict__ out, int* __restrict__ done) {
  if (done[blockIdx.x]) return;
  __shared__ u64 xch[2][4];
  __shared__ u64 fin[TMW];
  __shared__ int pfx[TMW];
  __shared__ int s_tot;
  const int NL = (TMW + 1) / 2;  // lanes holding keep-words (2 per lane)
  int b = blockIdx.x;
  int tid = threadIdx.x;
  int lane = tid & 63;
  int wv = tid >> 6;
  const u64* Mb = M + (size_t)b * KPRE * MSTRIDE;

  if (tid < TMW) fin[tid] = 0ull;

  u64 kw0 = ~0ull, kw1 = ~0ull;
  u64 cur = ~0ull;
  u64 dw = Mb[(size_t)lane * MSTRIDE + 0];
  int count = 0;
  ulonglong2 mmA[16], mmB[16];

  {
    bool la = (lane < NL);
    #pragma unroll
    for (int kk = 0; kk < 16; ++kk) {
      int r = wv + (kk << 2);
      ulonglong2 t2; t2.x = 0ull; t2.y = 0ull;
      if (la && r < KPRE) t2 = ((const ulonglong2*)(Mb + (size_t)r * MSTRIDE))[lane];
      mmA[kk] = t2;
    }
  }

#define SCAN_BODY(MMCUR, MMNXT)                                                         \
  {                                                                                     \
    int rem = KPRE - (w << 6);                                                          \
    u64 valid = (rem >= 64) ? ~0ull : ((1ull << rem) - 1ull);                           \
    cur &= valid;                                                                       \
    u64 nz = __ballot(dw != 0ull);                                                      \
    u64 pend = cur & nz;                                                                \
    while (pend) {                                                                      \
      int k = (int)__builtin_ctzll(pend);                                               \
      u64 d = bcast64(dw, k);                                                           \
      cur &= ~d;                                                                        \
      pend &= (pend - 1);                                                               \
      pend &= cur;                                                                      \
    }                                                                                   \
    if (tid == 0) fin[w] = cur;                                                         \
    count += (int)__popcll(cur);                                                        \
    if (count >= PROP || w == TMW - 1) break;                                           \
    {                                                                                   \
      int rn = ((w + 1) << 6) + lane;                                                   \
      dw = (rn < KPRE) ? Mb[(size_t)rn * MSTRIDE + (w + 1)] : 0ull;                     \
    }                                                                                   \
    {                                                                                   \
      bool la = (lane < NL) && (2 * lane + 1 >= w + 2);                                 \
      _Pragma("unroll")                                                                 \
      for (int kk = 0; kk < 16; ++kk) {                                                 \
        int r = ((w + 1) << 6) + wv + (kk << 2);                                        \
        ulonglong2 t2; t2.x = 0ull; t2.y = 0ull;                                        \
        if (la && r < KPRE) t2 = ((const ulonglong2*)(Mb + (size_t)r * MSTRIDE))[lane]; \
        MMNXT[kk] = t2;                                                                 \
      }                                                                                 \
    }                                                                                   \
    _Pragma("unroll")                                                                   \
    for (int kk = 0; kk < 16; ++kk) {                                                   \
      int k = wv + (kk << 2);                                                           \
      u64 sel = 0ull - ((cur >> k) & 1ull);                                             \
      kw0 &= ~(MMCUR[kk].x & sel);                                                      \
      kw1 &= ~(MMCUR[kk].y & sel);                                                      \
    }                                                                                   \
    int nw = w + 1;                                                                     \
    if (lane == (nw >> 1)) xch[nw & 1][wv] = (nw & 1) ? kw1 : kw0;                      \
    asm volatile("s_waitcnt lgkmcnt(0)" ::: "memory");                                  \
    __builtin_amdgcn_sched_barrier(0);                                                  \
    __builtin_amdgcn_s_barrier();                                                       \
    __builtin_amdgcn_sched_barrier(0);                                                  \
    cur = xch[nw & 1][0] & xch[nw & 1][1] & xch[nw & 1][2] & xch[nw & 1][3];            \
  }

  for (int w = 0; w < TMW; ++w) {
    if ((w & 1) == 0) SCAN_BODY(mmA, mmB)
    else              SCAN_BODY(mmB, mmA)
  }
#undef SCAN_BODY
  __syncthreads();

  if (tid == 0) {
    int s = 0;
    for (int t = 0; t < TMW; ++t) { pfx[t] = s; s += (int)__popcll(fin[t]); }
    s_tot = (s < PROP) ? s : PROP;
  }
  __syncthreads();

  const float4* bb = boxes + (size_t)b * KPRE;
  float4* ob = out + (size_t)b * PROP;
  if (tid < TMW) {
    u64 bits = fin[tid];
    int slot = pfx[tid];
    while (bits && slot < PROP) {
      int k = (int)__builtin_ctzll(bits);
      ob[slot] = bb[(tid << 6) + k];
      ++slot;
      bits &= bits - 1;
    }
  }
  {
    float4 z; z.x = 0.f; z.y = 0.f; z.z = 0.f; z.w = 0.f;
    for (int i = s_tot + tid; i < PROP; i += 256) ob[i] = z;
  }
}

extern "C" void kernel_launch(void* const* d_in, const int* in_sizes, int n_in,
                              void* d_out, int out_size, void* d_ws, size_t ws_size,
                              hipStream_t stream) {
  const float* probs   = (const float*)d_in[0];
  const float* bbox    = (const float*)d_in[1];
  const float* anchors = (const float*)d_in[2];
  char* ws = (char*)d_ws;
  u32* coarse  = (u32*)(ws + OFF_COARSE);        // u32[8][HB][256], fully overwritten
  int* meta    = (int*)(ws + OFF_META);          // T[8]
  int* cnt     = (int*)(ws + OFF_META + 4096);   // cnt[b*32], 128B-padded
  int* done    = (int*)(ws + OFF_META + 16384);  // done[8]
  int* ecnt    = (int*)(ws + OFF_META + 16512);  // ecnt[b*32], 128B-padded
  u32* elist   = (u32*)(ws + OFF_META + 20480);  // u32[8][EMAX] = 32 KB
  u64* cand    = (u64*)(ws + OFF_CAND);
  float4* boxes = (float4*)(ws + OFF_BOXES);
  u64* M       = (u64*)(ws + OFF_M);
  u16* histr   = (u16*)(ws + OFF_M);             // reuse M region (dead until k_mask)
  float4* out  = (float4*)d_out;

  // no hipMemsetAsync: coarse is fully overwritten by k_hist; cnt/ecnt/done zeroed by k_thresh.

  dim3 gh(HB, BATCH);
  k_hist<<<gh, 1024, 0, stream>>>(probs, histr, coarse);
  k_thresh<<<BATCH, 256, 0, stream>>>(histr, coarse, meta, cnt, ecnt, done);
  dim3 gc((NANCH / 2 + 255) / 256, BATCH);
  k_compact<<<gc, 256, 0, stream>>>(probs, meta, cnt, cand);
  dim3 gl(8, BATCH);
  k_lsort<<<gl, 1024, 0, stream>>>(cand, cnt);
  dim3 gmr(2, BATCH);
  k_merge<<<gmr, 1024, 0, stream>>>(cand, anchors, bbox, boxes);

  // phase 1: 4-word x 256-row tiles (55/batch, 440 blocks) -> ~1.7 waves/SIMD, same staging
  dim3 g1(NTILE1, BATCH);
  k_mask_t<4, R1 / 256, MW1 / 4, NTILE1, true><<<g1, 256, 0, stream>>>(boxes, M, elist, ecnt, done);
  k_scan1<MW1><<<BATCH, 64, 0, stream>>>(elist, ecnt, boxes, out, done);

  // phase 2: exact fallback (8-word tiles; early-exits per batch when done)
  dim3 g2(NTILE, BATCH);
  k_mask_t<8, 24, 12, NTILE, false><<<g2, 256, 0, stream>>>(boxes, M, elist, ecnt, done);
  k_scan_t<MW><<<BATCH, 256, 0, stream>>>(M, boxes, out, done);
}